// Round 8
// baseline (3867.414 us; speedup 1.0000x reference)
//
#include <hip/hip_runtime.h>
#include <hip/hip_bf16.h>

#define USER_NUM 100000
#define N_NODES  150000
#define EMB      64
#define NNZ      6400000
#define MATF ((size_t)N_NODES * EMB)   // elems per matrix (9.6M)

#define RPB1   512                      // rows per coarse bucket (row>>9)
#define NB1    ((N_NODES + RPB1 - 1) / RPB1)   // 293
#define CHUNK1 4096                     // edges staged per block in P1
#define NCB    19                       // column blocks of 8192 (col>>13)
#define NCELL  (RPB1 * NCB)             // 9728 p2 LDS cells

// ---------------------------------------------------------------------------
// Threefry-2x32, 20 rounds (JAX-compatible; verified passing).
// ---------------------------------------------------------------------------
__host__ __device__ __forceinline__ void tf_block(unsigned k0, unsigned k1,
                                                  unsigned x0, unsigned x1,
                                                  unsigned& o0, unsigned& o1) {
    unsigned ks[3] = {k0, k1, k0 ^ k1 ^ 0x1BD11BDAu};
    unsigned X0 = x0 + ks[0];
    unsigned X1 = x1 + ks[1];
    const int R[2][4] = {{13, 15, 26, 6}, {17, 29, 16, 24}};
#pragma unroll
    for (int i = 0; i < 5; ++i) {
        const int* r = R[i & 1];
#pragma unroll
        for (int j = 0; j < 4; ++j) {
            X0 += X1;
            X1 = (X1 << r[j]) | (X1 >> (32 - r[j]));
            X1 ^= X0;
        }
        X0 += ks[(i + 1) % 3];
        X1 += ks[(i + 2) % 3] + (unsigned)(i + 1);
    }
    o0 = X0; o1 = X1;
}

__device__ __forceinline__ unsigned short f_to_bfu(float f) {
    __hip_bfloat16 b = __float2bfloat16(f);   // RNE
    return *(unsigned short*)&b;
}
__device__ __forceinline__ float bfu_to_f(unsigned short u) {
    return __uint_as_float((unsigned)u << 16);
}

// ---------------------------------------------------------------------------
// Bucket-level histogram (293 counters, L2-resident) + tiny scan.
// ---------------------------------------------------------------------------
__global__ __launch_bounds__(256) void bhist_k(const int* __restrict__ rows,
                                               int* __restrict__ bb) {
    int e = blockIdx.x * 256 + threadIdx.x;
    if (e < NNZ) atomicAdd(&bb[rows[e] >> 9], 1);
}

__global__ __launch_bounds__(512) void bscan_k(int* __restrict__ bb,
                                               int* __restrict__ bcur) {
    __shared__ int sh[512];
    int t = threadIdx.x;
    int v = (t < NB1) ? bb[t] : 0;
    sh[t] = v;
    __syncthreads();
    for (int off = 1; off < 512; off <<= 1) {
        int x = (t >= off) ? sh[t - off] : 0;
        __syncthreads();
        sh[t] += x;
        __syncthreads();
    }
    int ex = sh[t] - v;  // exclusive prefix
    if (t < NB1) { bb[t] = ex; bcur[t] = ex; }
    if (t == NB1 - 1) bb[NB1] = sh[t];   // sentinel = NNZ
}

// ---------------------------------------------------------------------------
// P1: LDS-staged coarse scatter (write-combined). One block per 4096-edge
// chunk: LDS histogram over 293 buckets -> scan -> LDS reorder -> per-bucket
// global reservation -> flush bucket-contiguous runs (coalesced writes).
// tmp payload: x = col | (row & 511) << 18, y = bits(val).
// ---------------------------------------------------------------------------
__global__ __launch_bounds__(256) void p1_k(const int* __restrict__ rows,
                                            const int* __restrict__ cols,
                                            const float* __restrict__ vals,
                                            int* __restrict__ bcur,
                                            int2* __restrict__ tmp) {
    __shared__ int2 stage[CHUNK1];               // 32 KB
    __shared__ unsigned short sb[CHUNK1];        // 8 KB: bucket id per slot
    __shared__ int hist[NB1], lbase[NB1], lcur[NB1], gbase[NB1];
    const int tid = threadIdx.x;
    const int c0 = blockIdx.x * CHUNK1;
    const int n = (c0 + CHUNK1 <= NNZ) ? CHUNK1 : (NNZ - c0);

    for (int b = tid; b < NB1; b += 256) hist[b] = 0;
    __syncthreads();

    // load my edges (coalesced), histogram
    int2 pay[CHUNK1 / 256];
    int  pb[CHUNK1 / 256];
#pragma unroll
    for (int k = 0; k < CHUNK1 / 256; ++k) {
        int i = tid + k * 256;
        if (i < n) {
            int e = c0 + i;
            int r = rows[e];
            int b = r >> 9;
            pay[k] = make_int2(cols[e] | ((r & 511) << 18),
                               __float_as_int(vals[e]));
            pb[k] = b;
            atomicAdd(&hist[b], 1);
        } else pb[k] = -1;
    }
    __syncthreads();

    // exclusive scan over 293 buckets (single thread: ~300 adds, negligible)
    if (tid == 0) {
        int run = 0;
        for (int b = 0; b < NB1; ++b) {
            lbase[b] = run;
            lcur[b] = run;
            run += hist[b];
        }
    }
    __syncthreads();
    // global space reservation: one atomic per non-empty bucket per chunk
    for (int b = tid; b < NB1; b += 256)
        if (hist[b] > 0) gbase[b] = atomicAdd(&bcur[b], hist[b]);
    __syncthreads();

    // place into LDS, bucket-sorted
#pragma unroll
    for (int k = 0; k < CHUNK1 / 256; ++k) {
        if (pb[k] >= 0) {
            int pos = atomicAdd(&lcur[pb[k]], 1);
            stage[pos] = pay[k];
            sb[pos] = (unsigned short)pb[k];
        }
    }
    __syncthreads();

    // flush: consecutive i within a bucket -> consecutive global addresses
    for (int i = tid; i < n; i += 256) {
        int b = sb[i];
        tmp[gbase[b] + (i - lbase[b])] = stage[i];
    }
}

// ---------------------------------------------------------------------------
// P2: one block per coarse bucket. LDS histogram over (512 rows x 19
// colblocks), LDS scan -> exact (row, colblock)-sorted scatter into the
// bucket's contiguous slice of edges[] (write window ~175 KB, L2-resident).
// Emits per-row END offsets cur[]. Within-row colblock order gives the SpMM
// gather phase-aligned L2 locality (3.1 MB source slice per colblock).
// ---------------------------------------------------------------------------
__global__ __launch_bounds__(256) void p2_k(const int* __restrict__ bb,
                                            const int2* __restrict__ tmp,
                                            int2* __restrict__ edges,
                                            int* __restrict__ cur) {
    __shared__ int lh[NCELL];     // 38.9 KB
    __shared__ int ps[256];
    int b = blockIdx.x;
    int tid = threadIdx.x;
    int base = bb[b];
    int cnt = bb[b + 1] - base;

    for (int i = tid; i < NCELL; i += 256) lh[i] = 0;
    __syncthreads();

    for (int i = tid; i < cnt; i += 256) {
        int x = tmp[base + i].x;
        int cell = ((x >> 18) & 511) * NCB + ((x & 0x3FFFF) >> 13);
        atomicAdd(&lh[cell], 1);
    }
    __syncthreads();

    // exclusive scan of lh -> absolute start offsets (+base)
    const int PC = (NCELL + 255) / 256;   // 38
    int lo = tid * PC;
    int hi = lo + PC < NCELL ? lo + PC : NCELL;
    int s = 0;
    for (int i = lo; i < hi; ++i) s += lh[i];
    ps[tid] = s;
    __syncthreads();
    for (int off = 1; off < 256; off <<= 1) {
        int x = (tid >= off) ? ps[tid - off] : 0;
        __syncthreads();
        ps[tid] += x;
        __syncthreads();
    }
    int run = base + ps[tid] - s;
    for (int i = lo; i < hi; ++i) {
        int d = lh[i];
        lh[i] = run;
        run += d;
    }
    __syncthreads();

    // scatter to final (row, colblock)-sorted positions
    for (int i = tid; i < cnt; i += 256) {
        int2 w = tmp[base + i];
        int cell = ((w.x >> 18) & 511) * NCB + ((w.x & 0x3FFFF) >> 13);
        int pos = atomicAdd(&lh[cell], 1);
        edges[pos] = make_int2(w.x & 0x3FFFF, w.y);
    }
    __syncthreads();

    // after scatter every cell cursor == cell end; row end = last cell's end
    int r0 = b * RPB1;
    for (int t = tid; t < RPB1; t += 256) {
        int r = r0 + t;
        if (r < N_NODES) cur[r] = lh[t * NCB + (NCB - 1)];
    }
}

// ---------------------------------------------------------------------------
// Pack layer-0 sources: pE = bf16(ego), pIT = bf16(img) | bf16(txt)<<16
// ---------------------------------------------------------------------------
__global__ __launch_bounds__(256) void pack0_k(
    const float* __restrict__ user, const float* __restrict__ item,
    const float* __restrict__ image, const float* __restrict__ text,
    unsigned short* __restrict__ pE, unsigned* __restrict__ pIT) {
    size_t idx = (size_t)blockIdx.x * 256 + threadIdx.x;
    if (idx >= MATF) return;
    int row = (int)(idx >> 6);
    float e, i, t;
    if (row < USER_NUM) {
        float u = user[idx];
        e = u; i = u; t = u;
    } else {
        size_t cc = idx - (size_t)USER_NUM * EMB;
        e = item[cc]; i = image[cc]; t = text[cc];
    }
    pE[idx]  = f_to_bfu(e);
    pIT[idx] = (unsigned)f_to_bfu(i) | ((unsigned)f_to_bfu(t) << 16);
}

// ---------------------------------------------------------------------------
// Fused SpMM (3 matrices, packed bf16 sources) + leaky-relu + threefry
// dropout + l2norm + output accumulation. One wave per row; lane == dim.
// ---------------------------------------------------------------------------
__global__ __launch_bounds__(256) void spmm_post(
    const int* __restrict__ cur, const int2* __restrict__ edges,
    const unsigned short* __restrict__ sE, const unsigned* __restrict__ sIT,
    unsigned short* __restrict__ dE, unsigned* __restrict__ dIT,
    const float* __restrict__ w, float* __restrict__ out,
    unsigned ki0, unsigned ki1, unsigned kt0, unsigned kt1,
    int writeBack, int first) {
    int row = (int)((blockIdx.x * 256u + threadIdx.x) >> 6);
    int lane = threadIdx.x & 63;
    if (row >= N_NODES) return;
    int beg = __builtin_amdgcn_readfirstlane((row == 0) ? 0 : cur[row - 1]);
    int end = __builtin_amdgcn_readfirstlane(cur[row]);
    float ae = 0.f, ai = 0.f, at = 0.f;
#pragma unroll 8
    for (int i = beg; i < end; ++i) {
        int2 cv = edges[i];            // wave-uniform 8B load
        size_t cc = (size_t)cv.x * EMB + lane;
        float v = __int_as_float(cv.y);
        float xe = bfu_to_f(sE[cc]);
        unsigned it = sIT[cc];
        float xi = __uint_as_float(it << 16);
        float xt = __uint_as_float(it & 0xffff0000u);
        ae += v * xe; ai += v * xi; at += v * xt;
    }

    size_t idx = (size_t)row * EMB + lane;
    unsigned j = (unsigned)idx;

    float iv = ai >= 0.f ? ai : 0.01f * ai;      // leaky_relu
    float tv = at >= 0.f ? at : 0.01f * at;
    unsigned y0, y1;
    tf_block(ki0, ki1, 0u, j, y0, y1);
    iv = ((y0 ^ y1) >> 31) ? 0.f : iv * 2.f;     // dropout p=0.5, keep iff MSB==0
    tf_block(kt0, kt1, 0u, j, y0, y1);
    tv = ((y0 ^ y1) >> 31) ? 0.f : tv * 2.f;

    if (writeBack) {                              // next layer's SpMM inputs
        dE[idx]  = f_to_bfu(ae);
        dIT[idx] = (unsigned)f_to_bfu(iv) | ((unsigned)f_to_bfu(tv) << 16);
    }

    // row-wise l2 norms across the 64 lanes (full f32 values)
    float si = iv * iv, st2 = tv * tv;
#pragma unroll
    for (int m = 1; m < 64; m <<= 1) {
        si  += __shfl_xor(si, m, 64);
        st2 += __shfl_xor(st2, m, 64);
    }
    float ni = iv / fmaxf(sqrtf(si), 1e-12f);
    float nt = tv / fmaxf(sqrtf(st2), 1e-12f);

    const float inv3 = 1.0f / 3.0f;
    float contrib = (row < USER_NUM) ? ae * inv3
                                     : (w[0] * ae + w[1] * ni + w[2] * nt) * inv3;
    if (first) out[idx] = contrib;               // layer 0 overwrites (no memset)
    else       out[idx] += contrib;
}

// ---------------------------------------------------------------------------
extern "C" void kernel_launch(void* const* d_in, const int* in_sizes, int n_in,
                              void* d_out, int out_size, void* d_ws, size_t ws_size,
                              hipStream_t stream) {
    const float* user  = (const float*)d_in[0];
    const float* item  = (const float*)d_in[1];
    const float* image = (const float*)d_in[2];
    const float* text  = (const float*)d_in[3];
    const float* w     = (const float*)d_in[4];
    const float* vals  = (const float*)d_in[5];
    const int*   rows  = (const int*)d_in[6];
    const int*   cols  = (const int*)d_in[7];
    float* out = (float*)d_out;

    // workspace layout (~167 MB)
    int2* edges = (int2*)d_ws;                               // NNZ * 8B
    unsigned short* eA = (unsigned short*)(edges + NNZ);     // E ping (bf16)
    unsigned short* eB = eA + MATF;                          // E pong
    unsigned* itA = (unsigned*)(eB + MATF);                  // IT ping (2xbf16)
    unsigned* itB = itA + MATF;                              // IT pong
    int* cur  = (int*)(itB + MATF);                          // N_NODES
    int* bb   = cur + N_NODES;                               // NB1 + 1
    int* bcur = bb + (NB1 + 2);                              // NB1
    // tmp bucket buffer aliased onto (eB, itA): dead before pack0/spmm run.
    int2* tmp = (int2*)eB;                                   // NNZ * 8B

    // ---- CSR build: bucket hist/scan + write-combined 2-pass sort ----
    hipMemsetAsync(bb, 0, (NB1 + 1) * sizeof(int), stream);
    bhist_k<<<NNZ / 256, 256, 0, stream>>>(rows, bb);
    bscan_k<<<1, 512, 0, stream>>>(bb, bcur);
    p1_k<<<(NNZ + CHUNK1 - 1) / CHUNK1, 256, 0, stream>>>(rows, cols, vals,
                                                          bcur, tmp);
    p2_k<<<NB1, 256, 0, stream>>>(bb, tmp, edges, cur);

    const int blocks = (int)((MATF + 255) / 256);  // 37500: one wave per row
    pack0_k<<<blocks, 256, 0, stream>>>(user, item, image, text, eA, itA);

    unsigned short* sE = eA; unsigned* sIT = itA;
    unsigned short* dE = eB; unsigned* dIT = itB;
    for (int k = 0; k < 3; ++k) {
        unsigned f0, f1, a0, a1, b0, b1;
        tf_block(0u, 42u, 0u, (unsigned)k, f0, f1);
        tf_block(f0, f1, 0u, 0u, a0, a1);
        tf_block(f0, f1, 0u, 1u, b0, b1);
        int writeBack = (k < 2) ? 1 : 0;
        spmm_post<<<blocks, 256, 0, stream>>>(
            cur, edges, sE, sIT, dE, dIT, w, out, a0, a1, b0, b1,
            writeBack, k == 0 ? 1 : 0);
        // swap ping/pong
        unsigned short* te = sE; unsigned* tit = sIT;
        sE = dE; sIT = dIT;
        dE = te; dIT = tit;
    }
}

// Round 9
// 1280.367 us; speedup vs baseline: 3.0206x; 3.0206x over previous
//
#include <hip/hip_runtime.h>
#include <hip/hip_bf16.h>

#define USER_NUM 100000
#define N_NODES  150000
#define EMB      64
#define NNZ      6400000
#define MATF ((size_t)N_NODES * EMB)   // elems per matrix (9.6M)

#define RPB1   512                      // rows per coarse bucket (row>>9)
#define NB1    ((N_NODES + RPB1 - 1) / RPB1)   // 293
#define CHUNK1 4096                     // edges staged per block in P1
#define NCB    19                       // column blocks of 8192 (col>>13)
#define NCELL  (RPB1 * NCB)             // 9728 p2 LDS cells

// ---------------------------------------------------------------------------
// Threefry-2x32, 20 rounds (JAX-compatible; verified passing).
// ---------------------------------------------------------------------------
__host__ __device__ __forceinline__ void tf_block(unsigned k0, unsigned k1,
                                                  unsigned x0, unsigned x1,
                                                  unsigned& o0, unsigned& o1) {
    unsigned ks[3] = {k0, k1, k0 ^ k1 ^ 0x1BD11BDAu};
    unsigned X0 = x0 + ks[0];
    unsigned X1 = x1 + ks[1];
    const int R[2][4] = {{13, 15, 26, 6}, {17, 29, 16, 24}};
#pragma unroll
    for (int i = 0; i < 5; ++i) {
        const int* r = R[i & 1];
#pragma unroll
        for (int j = 0; j < 4; ++j) {
            X0 += X1;
            X1 = (X1 << r[j]) | (X1 >> (32 - r[j]));
            X1 ^= X0;
        }
        X0 += ks[(i + 1) % 3];
        X1 += ks[(i + 2) % 3] + (unsigned)(i + 1);
    }
    o0 = X0; o1 = X1;
}

__device__ __forceinline__ unsigned short f_to_bfu(float f) {
    __hip_bfloat16 b = __float2bfloat16(f);   // RNE
    return *(unsigned short*)&b;
}
__device__ __forceinline__ float bfu_to_f(unsigned short u) {
    return __uint_as_float((unsigned)u << 16);
}

// ---------------------------------------------------------------------------
// Bucket histogram, LDS-aggregated: per-block LDS hist over 293 buckets,
// then <=293 global atomics per block (kills the 6.4M-on-293 contention).
// ---------------------------------------------------------------------------
#define BHIST_BLOCKS 2048
__global__ __launch_bounds__(256) void bhist_k(const int* __restrict__ rows,
                                               int* __restrict__ bb) {
    __shared__ int h[NB1];
    for (int i = threadIdx.x; i < NB1; i += 256) h[i] = 0;
    __syncthreads();
    const int stride = BHIST_BLOCKS * 256;
    for (int e = blockIdx.x * 256 + threadIdx.x; e < NNZ; e += stride)
        atomicAdd(&h[rows[e] >> 9], 1);
    __syncthreads();
    for (int i = threadIdx.x; i < NB1; i += 256)
        if (h[i]) atomicAdd(&bb[i], h[i]);
}

__global__ __launch_bounds__(512) void bscan_k(int* __restrict__ bb,
                                               int* __restrict__ bcur) {
    __shared__ int sh[512];
    int t = threadIdx.x;
    int v = (t < NB1) ? bb[t] : 0;
    sh[t] = v;
    __syncthreads();
    for (int off = 1; off < 512; off <<= 1) {
        int x = (t >= off) ? sh[t - off] : 0;
        __syncthreads();
        sh[t] += x;
        __syncthreads();
    }
    int ex = sh[t] - v;  // exclusive prefix
    if (t < NB1) { bb[t] = ex; bcur[t] = ex; }
    if (t == NB1 - 1) bb[NB1] = sh[t];   // sentinel = NNZ
}

// ---------------------------------------------------------------------------
// P1: LDS-staged coarse scatter (write-combined). One block per 4096-edge
// chunk: LDS histogram over 293 buckets -> scan -> LDS reorder -> per-bucket
// global reservation -> flush bucket-contiguous runs (coalesced writes).
// tmp payload: x = col | (row & 511) << 18, y = bits(val).
// ---------------------------------------------------------------------------
__global__ __launch_bounds__(256) void p1_k(const int* __restrict__ rows,
                                            const int* __restrict__ cols,
                                            const float* __restrict__ vals,
                                            int* __restrict__ bcur,
                                            int2* __restrict__ tmp) {
    __shared__ int2 stage[CHUNK1];               // 32 KB
    __shared__ unsigned short sb[CHUNK1];        // 8 KB: bucket id per slot
    __shared__ int hist[NB1], lbase[NB1], lcur[NB1], gbase[NB1];
    const int tid = threadIdx.x;
    const int c0 = blockIdx.x * CHUNK1;
    const int n = (c0 + CHUNK1 <= NNZ) ? CHUNK1 : (NNZ - c0);

    for (int b = tid; b < NB1; b += 256) hist[b] = 0;
    __syncthreads();

    // load my edges (coalesced), histogram
    int2 pay[CHUNK1 / 256];
    int  pb[CHUNK1 / 256];
#pragma unroll
    for (int k = 0; k < CHUNK1 / 256; ++k) {
        int i = tid + k * 256;
        if (i < n) {
            int e = c0 + i;
            int r = rows[e];
            int b = r >> 9;
            pay[k] = make_int2(cols[e] | ((r & 511) << 18),
                               __float_as_int(vals[e]));
            pb[k] = b;
            atomicAdd(&hist[b], 1);
        } else pb[k] = -1;
    }
    __syncthreads();

    // exclusive scan over 293 buckets (single thread: ~300 adds, negligible)
    if (tid == 0) {
        int run = 0;
        for (int b = 0; b < NB1; ++b) {
            lbase[b] = run;
            lcur[b] = run;
            run += hist[b];
        }
    }
    __syncthreads();
    // global space reservation: one atomic per non-empty bucket per chunk
    for (int b = tid; b < NB1; b += 256)
        if (hist[b] > 0) gbase[b] = atomicAdd(&bcur[b], hist[b]);
    __syncthreads();

    // place into LDS, bucket-sorted
#pragma unroll
    for (int k = 0; k < CHUNK1 / 256; ++k) {
        if (pb[k] >= 0) {
            int pos = atomicAdd(&lcur[pb[k]], 1);
            stage[pos] = pay[k];
            sb[pos] = (unsigned short)pb[k];
        }
    }
    __syncthreads();

    // flush: consecutive i within a bucket -> consecutive global addresses
    for (int i = tid; i < n; i += 256) {
        int b = sb[i];
        tmp[gbase[b] + (i - lbase[b])] = stage[i];
    }
}

// ---------------------------------------------------------------------------
// P2: one block per coarse bucket. LDS histogram over (512 rows x 19
// colblocks), LDS scan -> exact (row, colblock)-sorted scatter into the
// bucket's contiguous slice of edges[] (write window ~175 KB, L2-resident).
// Emits per-row END offsets cur[]. Within-row colblock order gives the SpMM
// gather phase-aligned L2 locality (3.1 MB source slice per colblock).
// ---------------------------------------------------------------------------
__global__ __launch_bounds__(256) void p2_k(const int* __restrict__ bb,
                                            const int2* __restrict__ tmp,
                                            int2* __restrict__ edges,
                                            int* __restrict__ cur) {
    __shared__ int lh[NCELL];     // 38.9 KB
    __shared__ int ps[256];
    int b = blockIdx.x;
    int tid = threadIdx.x;
    int base = bb[b];
    int cnt = bb[b + 1] - base;

    for (int i = tid; i < NCELL; i += 256) lh[i] = 0;
    __syncthreads();

    for (int i = tid; i < cnt; i += 256) {
        int x = tmp[base + i].x;
        int cell = ((x >> 18) & 511) * NCB + ((x & 0x3FFFF) >> 13);
        atomicAdd(&lh[cell], 1);
    }
    __syncthreads();

    // exclusive scan of lh -> absolute start offsets (+base)
    const int PC = (NCELL + 255) / 256;   // 38
    int lo = tid * PC;
    int hi = lo + PC < NCELL ? lo + PC : NCELL;
    int s = 0;
    for (int i = lo; i < hi; ++i) s += lh[i];
    ps[tid] = s;
    __syncthreads();
    for (int off = 1; off < 256; off <<= 1) {
        int x = (tid >= off) ? ps[tid - off] : 0;
        __syncthreads();
        ps[tid] += x;
        __syncthreads();
    }
    int run = base + ps[tid] - s;
    for (int i = lo; i < hi; ++i) {
        int d = lh[i];
        lh[i] = run;
        run += d;
    }
    __syncthreads();

    // scatter to final (row, colblock)-sorted positions
    for (int i = tid; i < cnt; i += 256) {
        int2 w = tmp[base + i];
        int cell = ((w.x >> 18) & 511) * NCB + ((w.x & 0x3FFFF) >> 13);
        int pos = atomicAdd(&lh[cell], 1);
        edges[pos] = make_int2(w.x & 0x3FFFF, w.y);
    }
    __syncthreads();

    // after scatter every cell cursor == cell end; row end = last cell's end
    int r0 = b * RPB1;
    for (int t = tid; t < RPB1; t += 256) {
        int r = r0 + t;
        if (r < N_NODES) cur[r] = lh[t * NCB + (NCB - 1)];
    }
}

// ---------------------------------------------------------------------------
// Pack layer-0 sources: pE = bf16(ego), pIT = bf16(img) | bf16(txt)<<16
// ---------------------------------------------------------------------------
__global__ __launch_bounds__(256) void pack0_k(
    const float* __restrict__ user, const float* __restrict__ item,
    const float* __restrict__ image, const float* __restrict__ text,
    unsigned short* __restrict__ pE, unsigned* __restrict__ pIT) {
    size_t idx = (size_t)blockIdx.x * 256 + threadIdx.x;
    if (idx >= MATF) return;
    int row = (int)(idx >> 6);
    float e, i, t;
    if (row < USER_NUM) {
        float u = user[idx];
        e = u; i = u; t = u;
    } else {
        size_t cc = idx - (size_t)USER_NUM * EMB;
        e = item[cc]; i = image[cc]; t = text[cc];
    }
    pE[idx]  = f_to_bfu(e);
    pIT[idx] = (unsigned)f_to_bfu(i) | ((unsigned)f_to_bfu(t) << 16);
}

// ---------------------------------------------------------------------------
// Fused SpMM (3 matrices, packed bf16 sources) + leaky-relu + threefry
// dropout + l2norm + output accumulation. One wave per row; lane == dim.
// ---------------------------------------------------------------------------
__global__ __launch_bounds__(256) void spmm_post(
    const int* __restrict__ cur, const int2* __restrict__ edges,
    const unsigned short* __restrict__ sE, const unsigned* __restrict__ sIT,
    unsigned short* __restrict__ dE, unsigned* __restrict__ dIT,
    const float* __restrict__ w, float* __restrict__ out,
    unsigned ki0, unsigned ki1, unsigned kt0, unsigned kt1,
    int writeBack, int first) {
    int row = (int)((blockIdx.x * 256u + threadIdx.x) >> 6);
    int lane = threadIdx.x & 63;
    if (row >= N_NODES) return;
    int beg = __builtin_amdgcn_readfirstlane((row == 0) ? 0 : cur[row - 1]);
    int end = __builtin_amdgcn_readfirstlane(cur[row]);
    float ae = 0.f, ai = 0.f, at = 0.f;
#pragma unroll 8
    for (int i = beg; i < end; ++i) {
        int2 cv = edges[i];            // wave-uniform 8B load
        size_t cc = (size_t)cv.x * EMB + lane;
        float v = __int_as_float(cv.y);
        float xe = bfu_to_f(sE[cc]);
        unsigned it = sIT[cc];
        float xi = __uint_as_float(it << 16);
        float xt = __uint_as_float(it & 0xffff0000u);
        ae += v * xe; ai += v * xi; at += v * xt;
    }

    size_t idx = (size_t)row * EMB + lane;
    unsigned j = (unsigned)idx;

    float iv = ai >= 0.f ? ai : 0.01f * ai;      // leaky_relu
    float tv = at >= 0.f ? at : 0.01f * at;
    unsigned y0, y1;
    tf_block(ki0, ki1, 0u, j, y0, y1);
    iv = ((y0 ^ y1) >> 31) ? 0.f : iv * 2.f;     // dropout p=0.5, keep iff MSB==0
    tf_block(kt0, kt1, 0u, j, y0, y1);
    tv = ((y0 ^ y1) >> 31) ? 0.f : tv * 2.f;

    if (writeBack) {                              // next layer's SpMM inputs
        dE[idx]  = f_to_bfu(ae);
        dIT[idx] = (unsigned)f_to_bfu(iv) | ((unsigned)f_to_bfu(tv) << 16);
    }

    // row-wise l2 norms across the 64 lanes (full f32 values)
    float si = iv * iv, st2 = tv * tv;
#pragma unroll
    for (int m = 1; m < 64; m <<= 1) {
        si  += __shfl_xor(si, m, 64);
        st2 += __shfl_xor(st2, m, 64);
    }
    float ni = iv / fmaxf(sqrtf(si), 1e-12f);
    float nt = tv / fmaxf(sqrtf(st2), 1e-12f);

    const float inv3 = 1.0f / 3.0f;
    float contrib = (row < USER_NUM) ? ae * inv3
                                     : (w[0] * ae + w[1] * ni + w[2] * nt) * inv3;
    if (first) out[idx] = contrib;               // layer 0 overwrites (no memset)
    else       out[idx] += contrib;
}

// ---------------------------------------------------------------------------
extern "C" void kernel_launch(void* const* d_in, const int* in_sizes, int n_in,
                              void* d_out, int out_size, void* d_ws, size_t ws_size,
                              hipStream_t stream) {
    const float* user  = (const float*)d_in[0];
    const float* item  = (const float*)d_in[1];
    const float* image = (const float*)d_in[2];
    const float* text  = (const float*)d_in[3];
    const float* w     = (const float*)d_in[4];
    const float* vals  = (const float*)d_in[5];
    const int*   rows  = (const int*)d_in[6];
    const int*   cols  = (const int*)d_in[7];
    float* out = (float*)d_out;

    // workspace layout (~167 MB)
    int2* edges = (int2*)d_ws;                               // NNZ * 8B
    unsigned short* eA = (unsigned short*)(edges + NNZ);     // E ping (bf16)
    unsigned short* eB = eA + MATF;                          // E pong
    unsigned* itA = (unsigned*)(eB + MATF);                  // IT ping (2xbf16)
    unsigned* itB = itA + MATF;                              // IT pong
    int* cur  = (int*)(itB + MATF);                          // N_NODES
    int* bb   = cur + N_NODES;                               // NB1 + 1
    int* bcur = bb + (NB1 + 2);                              // NB1
    // tmp bucket buffer aliased onto (eB, itA): dead before pack0/spmm run.
    int2* tmp = (int2*)eB;                                   // NNZ * 8B

    // ---- CSR build: bucket hist/scan + write-combined 2-pass sort ----
    hipMemsetAsync(bb, 0, (NB1 + 1) * sizeof(int), stream);
    bhist_k<<<BHIST_BLOCKS, 256, 0, stream>>>(rows, bb);
    bscan_k<<<1, 512, 0, stream>>>(bb, bcur);
    p1_k<<<(NNZ + CHUNK1 - 1) / CHUNK1, 256, 0, stream>>>(rows, cols, vals,
                                                          bcur, tmp);
    p2_k<<<NB1, 256, 0, stream>>>(bb, tmp, edges, cur);

    const int blocks = (int)((MATF + 255) / 256);  // 37500: one wave per row
    pack0_k<<<blocks, 256, 0, stream>>>(user, item, image, text, eA, itA);

    unsigned short* sE = eA; unsigned* sIT = itA;
    unsigned short* dE = eB; unsigned* dIT = itB;
    for (int k = 0; k < 3; ++k) {
        unsigned f0, f1, a0, a1, b0, b1;
        tf_block(0u, 42u, 0u, (unsigned)k, f0, f1);
        tf_block(f0, f1, 0u, 0u, a0, a1);
        tf_block(f0, f1, 0u, 1u, b0, b1);
        int writeBack = (k < 2) ? 1 : 0;
        spmm_post<<<blocks, 256, 0, stream>>>(
            cur, edges, sE, sIT, dE, dIT, w, out, a0, a1, b0, b1,
            writeBack, k == 0 ? 1 : 0);
        // swap ping/pong
        unsigned short* te = sE; unsigned* tit = sIT;
        sE = dE; sIT = dIT;
        dE = te; dIT = tit;
    }
}